// Round 5
// baseline (468.998 us; speedup 1.0000x reference)
//
#include <hip/hip_runtime.h>
#include <hip/hip_bf16.h>
#include <stddef.h>

// ---------------- problem constants ----------------
#define NTOK   16384          // b*n = 4*4096
#define SEQN   4096
#define DIM    1024
#define K3     3072           // 3*DIM
#define HEADS  16
#define HD     64             // head dim

typedef __attribute__((ext_vector_type(8))) short short8;
typedef __attribute__((ext_vector_type(4))) float float4v;

// gfx9 s_waitcnt immediate: vmcnt [3:0]+[15:14], expcnt [6:4], lgkmcnt [11:8]
#define WAIT_VMCNT(n) (((n) & 0xF) | (((n) >> 4) << 14) | (0x7 << 4) | (0xF << 8))

static __device__ __forceinline__ unsigned short f32_to_bf16_bits(float f) {
    unsigned u = __float_as_uint(f);
    unsigned r = u + 0x7fffu + ((u >> 16) & 1u);   // RNE
    return (unsigned short)(r >> 16);
}
static __device__ __forceinline__ unsigned pack_bf16x2(float lo, float hi) {
    return (unsigned)f32_to_bf16_bits(lo) | ((unsigned)f32_to_bf16_bits(hi) << 16);
}
static __device__ __forceinline__ void unpack_bf16x8(uint4 u, float* f) {
    f[0] = __uint_as_float(u.x << 16); f[1] = __uint_as_float(u.x & 0xffff0000u);
    f[2] = __uint_as_float(u.y << 16); f[3] = __uint_as_float(u.y & 0xffff0000u);
    f[4] = __uint_as_float(u.z << 16); f[5] = __uint_as_float(u.z & 0xffff0000u);
    f[6] = __uint_as_float(u.w << 16); f[7] = __uint_as_float(u.w & 0xffff0000u);
}

// async global->LDS DMA, 16B per lane, LDS dst = uniform base + lane*16
typedef const void __attribute__((address_space(1)))* gas_ptr;
typedef void __attribute__((address_space(3)))* las_ptr;
static __device__ __forceinline__ void gload_lds16(const unsigned short* g,
                                                   unsigned short* l) {
    __builtin_amdgcn_global_load_lds((gas_ptr)g, (las_ptr)l, 16, 0, 0);
}

// ---------------- prep: fp32 -> bf16 cast (vectorized) ----------------
__global__ void cvt_f32_bf16(const float4* __restrict__ in,
                             ushort4* __restrict__ out, int n4) {
    int i = blockIdx.x * blockDim.x + threadIdx.x;
    if (i < n4) {
        float4 v = in[i];
        ushort4 o;
        o.x = f32_to_bf16_bits(v.x);
        o.y = f32_to_bf16_bits(v.y);
        o.z = f32_to_bf16_bits(v.z);
        o.w = f32_to_bf16_bits(v.w);
        out[i] = o;
    }
}

// ---------------- prep: transpose K x N fp32 -> N x K bf16 ----------------
__global__ void transpose_cvt(const float* __restrict__ in,
                              unsigned short* __restrict__ out,
                              int K, int N) {
    __shared__ float t[32][33];
    int n0 = blockIdx.x * 32, k0 = blockIdx.y * 32;
    int tx = threadIdx.x, ty = threadIdx.y;     // block (32,8)
    #pragma unroll
    for (int r = ty; r < 32; r += 8)
        t[r][tx] = in[(size_t)(k0 + r) * N + n0 + tx];
    __syncthreads();
    #pragma unroll
    for (int r = ty; r < 32; r += 8)
        out[(size_t)(n0 + r) * K + k0 + tx] = f32_to_bf16_bits(t[tx][r]);
}

// ------------- barrier-free pipelined bf16 MFMA GEMM --------------
// C[M,N] = A[M,K] * Bt[N,K]^T.  Block = 128 threads = 2 waves covering
// 64 rows x 128 cols; each wave owns a 64x64 quadrant and a PRIVATE
// double-buffered LDS region staged with its own global_load_lds dwordx4.
// No __syncthreads.  Ordering is enforced EXPLICITLY (round-4 NaN lesson:
// the compiler emits NO wait between LDS-DMA and ds_read without a
// barrier): issue next-buffer DMAs (16 outstanding), s_waitcnt vmcnt(8)
// -> oldest 8 (current buffer) complete, fresh 8 stay in flight.
template<int WITH_BIAS>
__global__ __launch_bounds__(128, 2) void gemm_bf16_pipe(
    const unsigned short* __restrict__ A,
    const unsigned short* __restrict__ Bt,
    void* __restrict__ Cout,
    const float* __restrict__ bias,
    int M, int N, int K)
{
    // [wave][buf][A=0/B=1][row][col] : 2*2*2*64*32*2B = 32 KB
    __shared__ unsigned short lds[2][2][2][64][32];

    const int tid  = threadIdx.x;
    const int wv   = tid >> 6;
    const int lane = tid & 63;
    const int quad = lane >> 4;
    const int l16  = lane & 15;
    const int rowBase = blockIdx.y * 64;
    const int colBase = blockIdx.x * 128 + wv * 64;

    float4v acc[4][4];
    #pragma unroll
    for (int i = 0; i < 4; i++)
        #pragma unroll
        for (int j = 0; j < 4; j++)
            acc[i][j] = (float4v)0.0f;

    // DMA lane geometry: 16 rows x 32 cols per issue; lane -> (row=lane>>2,
    // col=(lane&3)*8 shorts) == LDS offset lane*16 B from the uniform base.
    const int lrow = lane >> 2;
    const int lcol = (lane & 3) * 8;
    const unsigned short* gA = A  + (size_t)(rowBase + lrow) * K + lcol;
    const unsigned short* gB = Bt + (size_t)(colBase + lrow) * K + lcol;
    const size_t k16 = (size_t)16 * K;

    const int nsteps = K >> 5;   // BK = 32
    int buf = 0;

    // prologue: stage buffer 0 with k0 = 0   (8 DMAs in flight)
    #pragma unroll
    for (int g = 0; g < 4; g++) {
        gload_lds16(gA + (size_t)g * k16, &lds[wv][0][0][g * 16][0]);
        gload_lds16(gB + (size_t)g * k16, &lds[wv][0][1][g * 16][0]);
    }

    for (int s = 0; s + 1 < nsteps; s++) {
        // issue DMAs for the NEXT buffer first: 16 outstanding
        const size_t k0 = (size_t)(s + 1) << 5;
        const int nb = buf ^ 1;
        #pragma unroll
        for (int g = 0; g < 4; g++) {
            gload_lds16(gA + k0 + (size_t)g * k16, &lds[wv][nb][0][g * 16][0]);
            gload_lds16(gB + k0 + (size_t)g * k16, &lds[wv][nb][1][g * 16][0]);
        }

        __builtin_amdgcn_sched_barrier(0);
        __builtin_amdgcn_s_waitcnt(WAIT_VMCNT(8));   // current buffer ready
        __builtin_amdgcn_sched_barrier(0);

        short8 af[4], bf[4];
        #pragma unroll
        for (int i = 0; i < 4; i++)
            af[i] = *(const short8*)&lds[wv][buf][0][i * 16 + l16][quad * 8];
        #pragma unroll
        for (int j = 0; j < 4; j++)
            bf[j] = *(const short8*)&lds[wv][buf][1][j * 16 + l16][quad * 8];

        #pragma unroll
        for (int i = 0; i < 4; i++)
            #pragma unroll
            for (int j = 0; j < 4; j++)
                acc[i][j] = __builtin_amdgcn_mfma_f32_16x16x32_bf16(
                                af[i], bf[j], acc[i][j], 0, 0, 0);
        buf ^= 1;
    }

    // peeled last K-step: nothing new in flight -> full per-wave drain
    {
        __builtin_amdgcn_sched_barrier(0);
        __builtin_amdgcn_s_waitcnt(WAIT_VMCNT(0));
        __builtin_amdgcn_sched_barrier(0);

        short8 af[4], bf[4];
        #pragma unroll
        for (int i = 0; i < 4; i++)
            af[i] = *(const short8*)&lds[wv][buf][0][i * 16 + l16][quad * 8];
        #pragma unroll
        for (int j = 0; j < 4; j++)
            bf[j] = *(const short8*)&lds[wv][buf][1][j * 16 + l16][quad * 8];

        #pragma unroll
        for (int i = 0; i < 4; i++)
            #pragma unroll
            for (int j = 0; j < 4; j++)
                acc[i][j] = __builtin_amdgcn_mfma_f32_16x16x32_bf16(
                                af[i], bf[j], acc[i][j], 0, 0, 0);
    }

    // epilogue: D[row][col], col = lane&15, row = quad*4 + r   (m89/m91)
    #pragma unroll
    for (int i = 0; i < 4; i++) {
        #pragma unroll
        for (int j = 0; j < 4; j++) {
            const int col = colBase + j * 16 + l16;
            #pragma unroll
            for (int r = 0; r < 4; r++) {
                const int row = rowBase + i * 16 + quad * 4 + r;
                float v = acc[i][j][r];
                if (WITH_BIAS) {
                    ((float*)Cout)[(size_t)row * N + col] = v + bias[col];
                } else {
                    ((unsigned short*)Cout)[(size_t)row * N + col] =
                        f32_to_bf16_bits(v);
                }
            }
        }
    }
}

// ---------------- per-token attention: wave-per-token, barrier-free --------
__global__ __launch_bounds__(256) void attn_tok(
    const unsigned short* __restrict__ qkv,   // NTOK x 3072 bf16
    const float* __restrict__ fcos,           // 4096 x 32
    const float* __restrict__ fsin,
    const float* __restrict__ gq,             // 64
    const float* __restrict__ gk,
    unsigned short* __restrict__ outb)        // NTOK x 1024 bf16
{
    __shared__ float kl[4][16][68];   // [wave][g][dim] stride 68: 2-way alias
    __shared__ float vl[4][16][68];

    const int tid  = threadIdx.x;
    const int wv   = tid >> 6;
    const int lane = tid & 63;
    const int h    = lane & 15;
    const int p    = lane >> 4;
    const int tok  = blockIdx.x * 4 + wv;
    const int n    = tok & (SEQN - 1);

    const unsigned short* base = qkv + (size_t)tok * K3 + h * 64 + p * 16;
    uint4 qr0 = *(const uint4*)(base);
    uint4 qr1 = *(const uint4*)(base + 8);
    uint4 kr0 = *(const uint4*)(base + DIM);
    uint4 kr1 = *(const uint4*)(base + DIM + 8);
    uint4 vr0 = *(const uint4*)(base + 2 * DIM);
    uint4 vr1 = *(const uint4*)(base + 2 * DIM + 8);

    float q[16], k[16], v[16];
    unpack_bf16x8(qr0, q); unpack_bf16x8(qr1, q + 8);
    unpack_bf16x8(kr0, k); unpack_bf16x8(kr1, k + 8);
    unpack_bf16x8(vr0, v); unpack_bf16x8(vr1, v + 8);

    // RMSNorm over the 64-dim head (reduce across the 4 p-slices)
    float ssq = 0.f, ssk = 0.f;
    #pragma unroll
    for (int i = 0; i < 16; i++) { ssq += q[i] * q[i]; ssk += k[i] * k[i]; }
    ssq += __shfl_xor(ssq, 16); ssq += __shfl_xor(ssq, 32);
    ssk += __shfl_xor(ssk, 16); ssk += __shfl_xor(ssk, 32);
    const float sq = 1.0f / (sqrtf(ssq) * 0.125f + 1e-6f);
    const float sk = 1.0f / (sqrtf(ssk) * 0.125f + 1e-6f);

    #pragma unroll
    for (int c = 0; c < 4; c++) {
        float4 gg = *(const float4*)(gq + p * 16 + c * 4);
        float4 gh = *(const float4*)(gk + p * 16 + c * 4);
        q[c*4+0] *= sq * gg.x; q[c*4+1] *= sq * gg.y;
        q[c*4+2] *= sq * gg.z; q[c*4+3] *= sq * gg.w;
        k[c*4+0] *= sk * gh.x; k[c*4+1] *= sk * gh.y;
        k[c*4+2] *= sk * gh.z; k[c*4+3] *= sk * gh.w;
    }

    // RoPE: local pair j -> global pair index 8p+j
    {
        const float* cb = fcos + n * 32 + p * 8;
        const float* sb = fsin + n * 32 + p * 8;
        float4 c0 = *(const float4*)cb, c1 = *(const float4*)(cb + 4);
        float4 s0 = *(const float4*)sb, s1 = *(const float4*)(sb + 4);
        float cs[8] = {c0.x,c0.y,c0.z,c0.w,c1.x,c1.y,c1.z,c1.w};
        float sn[8] = {s0.x,s0.y,s0.z,s0.w,s1.x,s1.y,s1.z,s1.w};
        #pragma unroll
        for (int j = 0; j < 8; j++) {
            float re = q[2*j], im = q[2*j+1];
            q[2*j]   = re * cs[j] - im * sn[j];
            q[2*j+1] = re * sn[j] + im * cs[j];
            re = k[2*j]; im = k[2*j+1];
            k[2*j]   = re * cs[j] - im * sn[j];
            k[2*j+1] = re * sn[j] + im * cs[j];
        }
    }

    // stage roped K and raw V into the per-wave LDS tile
    {
        float* krow = &kl[wv][h][p * 16];
        float* vrow = &vl[wv][h][p * 16];
        #pragma unroll
        for (int c = 0; c < 4; c++) {
            *(float4*)(krow + c*4) = make_float4(k[c*4], k[c*4+1], k[c*4+2], k[c*4+3]);
            *(float4*)(vrow + c*4) = make_float4(v[c*4], v[c*4+1], v[c*4+2], v[c*4+3]);
        }
    }

    // S[h][g] partial over this lane's 16 dims, then reduce across p
    float s[16];
    #pragma unroll
    for (int g = 0; g < 16; g++) {
        const float* kg = &kl[wv][g][p * 16];
        float4 a0 = *(const float4*)(kg);
        float4 a1 = *(const float4*)(kg + 4);
        float4 a2 = *(const float4*)(kg + 8);
        float4 a3 = *(const float4*)(kg + 12);
        s[g] = q[0]*a0.x + q[1]*a0.y + q[2]*a0.z + q[3]*a0.w
             + q[4]*a1.x + q[5]*a1.y + q[6]*a1.z + q[7]*a1.w
             + q[8]*a2.x + q[9]*a2.y + q[10]*a2.z + q[11]*a2.w
             + q[12]*a3.x + q[13]*a3.y + q[14]*a3.z + q[15]*a3.w;
    }
    #pragma unroll
    for (int g = 0; g < 16; g++) {
        s[g] += __shfl_xor(s[g], 16);
        s[g] += __shfl_xor(s[g], 32);
        s[g] *= 0.125f;
    }

    // lane-local softmax over g
    float m = s[0];
    #pragma unroll
    for (int g = 1; g < 16; g++) m = fmaxf(m, s[g]);
    float sum = 0.f;
    #pragma unroll
    for (int g = 0; g < 16; g++) { s[g] = __expf(s[g] - m); sum += s[g]; }
    const float inv = 1.0f / sum;

    // O[h][slice p] = sum_g P[g] * V[g][slice p]
    float o[16];
    #pragma unroll
    for (int i = 0; i < 16; i++) o[i] = 0.f;
    #pragma unroll
    for (int g = 0; g < 16; g++) {
        const float pg = s[g] * inv;
        const float* vg = &vl[wv][g][p * 16];
        float4 b0 = *(const float4*)(vg);
        float4 b1 = *(const float4*)(vg + 4);
        float4 b2 = *(const float4*)(vg + 8);
        float4 b3 = *(const float4*)(vg + 12);
        o[0]  += pg * b0.x; o[1]  += pg * b0.y; o[2]  += pg * b0.z; o[3]  += pg * b0.w;
        o[4]  += pg * b1.x; o[5]  += pg * b1.y; o[6]  += pg * b1.z; o[7]  += pg * b1.w;
        o[8]  += pg * b2.x; o[9]  += pg * b2.y; o[10] += pg * b2.z; o[11] += pg * b2.w;
        o[12] += pg * b3.x; o[13] += pg * b3.y; o[14] += pg * b3.z; o[15] += pg * b3.w;
    }

    uint4 r0, r1;
    r0.x = pack_bf16x2(o[0],  o[1]);  r0.y = pack_bf16x2(o[2],  o[3]);
    r0.z = pack_bf16x2(o[4],  o[5]);  r0.w = pack_bf16x2(o[6],  o[7]);
    r1.x = pack_bf16x2(o[8],  o[9]);  r1.y = pack_bf16x2(o[10], o[11]);
    r1.z = pack_bf16x2(o[12], o[13]); r1.w = pack_bf16x2(o[14], o[15]);
    unsigned short* ob = outb + (size_t)tok * DIM + h * 64 + p * 16;
    *(uint4*)(ob)     = r0;
    *(uint4*)(ob + 8) = r1;
}

// ---------------- launch ----------------
extern "C" void kernel_launch(void* const* d_in, const int* in_sizes, int n_in,
                              void* d_out, int out_size, void* d_ws, size_t ws_size,
                              hipStream_t stream) {
    const float* x      = (const float*)d_in[0];   // 16384 x 1024
    const float* fcos   = (const float*)d_in[1];   // 4096 x 32
    const float* fsin   = (const float*)d_in[2];
    const float* w_qkv  = (const float*)d_in[3];   // 1024 x 3072
    const float* g_q    = (const float*)d_in[4];
    const float* g_k    = (const float*)d_in[5];
    const float* w_proj = (const float*)d_in[6];   // 1024 x 1024
    const float* b_proj = (const float*)d_in[7];
    float* out = (float*)d_out;

    char* ws = (char*)d_ws;
    // workspace layout (bytes)
    unsigned short* xb      = (unsigned short*)(ws);                       // 33,554,432
    unsigned short* wqkvT   = (unsigned short*)(ws + 33554432);            //  6,291,456
    unsigned short* wprojT  = (unsigned short*)(ws + 39845888);            //  2,097,152
    unsigned short* qkv     = (unsigned short*)(ws + 41943040);            // 100,663,296
    unsigned short* attnout = (unsigned short*)(ws + 142606336);           // 33,554,432
    (void)ws_size; (void)in_sizes; (void)n_in; (void)out_size;

    // 1. casts / transposes
    {
        int n4 = (NTOK * DIM) / 4;   // 4,194,304
        cvt_f32_bf16<<<(n4 + 255) / 256, 256, 0, stream>>>(
            (const float4*)x, (ushort4*)xb, n4);
        transpose_cvt<<<dim3(K3 / 32, DIM / 32), dim3(32, 8), 0, stream>>>(
            w_qkv, wqkvT, DIM, K3);
        transpose_cvt<<<dim3(DIM / 32, DIM / 32), dim3(32, 8), 0, stream>>>(
            w_proj, wprojT, DIM, DIM);
    }
    // 2. qkv = x @ w_qkv   (bf16 out)   64-row x 128-col blocks
    gemm_bf16_pipe<0><<<dim3(K3 / 128, NTOK / 64), 128, 0, stream>>>(
        xb, wqkvT, (void*)qkv, nullptr, NTOK, K3, DIM);
    // 3. per-token attention (wave per token, 4 tokens/block)
    attn_tok<<<NTOK / 4, 256, 0, stream>>>(qkv, fcos, fsin, g_q, g_k, attnout);
    // 4. out = attn @ w_proj + b   (fp32 out)
    gemm_bf16_pipe<1><<<dim3(DIM / 128, NTOK / 64), 128, 0, stream>>>(
        attnout, wprojT, (void*)out, b_proj, NTOK, DIM, DIM);
}

// Round 6
// 361.182 us; speedup vs baseline: 1.2985x; 1.2985x over previous
//
#include <hip/hip_runtime.h>
#include <hip/hip_bf16.h>
#include <stddef.h>

// ---------------- problem constants ----------------
#define NTOK   16384          // b*n = 4*4096
#define SEQN   4096
#define DIM    1024
#define K3     3072           // 3*DIM
#define HEADS  16
#define HD     64             // head dim

typedef __attribute__((ext_vector_type(8)))  short  short8;
typedef __attribute__((ext_vector_type(16))) float  float16v;

static __device__ __forceinline__ unsigned short f32_to_bf16_bits(float f) {
    unsigned u = __float_as_uint(f);
    unsigned r = u + 0x7fffu + ((u >> 16) & 1u);   // RNE
    return (unsigned short)(r >> 16);
}
static __device__ __forceinline__ unsigned pack_bf16x2(float lo, float hi) {
    return (unsigned)f32_to_bf16_bits(lo) | ((unsigned)f32_to_bf16_bits(hi) << 16);
}
static __device__ __forceinline__ void unpack_bf16x8(uint4 u, float* f) {
    f[0] = __uint_as_float(u.x << 16); f[1] = __uint_as_float(u.x & 0xffff0000u);
    f[2] = __uint_as_float(u.y << 16); f[3] = __uint_as_float(u.y & 0xffff0000u);
    f[4] = __uint_as_float(u.z << 16); f[5] = __uint_as_float(u.z & 0xffff0000u);
    f[6] = __uint_as_float(u.w << 16); f[7] = __uint_as_float(u.w & 0xffff0000u);
}

// async global->LDS DMA, 16B per lane, LDS dst = uniform base + lane*16
typedef const void __attribute__((address_space(1)))* gas_ptr;
typedef void __attribute__((address_space(3)))* las_ptr;
static __device__ __forceinline__ void gload_lds16(const unsigned short* g,
                                                   unsigned short* l) {
    __builtin_amdgcn_global_load_lds((gas_ptr)g, (las_ptr)l, 16, 0, 0);
}

// ---------------- prep: fp32 -> bf16 cast (vectorized) ----------------
__global__ void cvt_f32_bf16(const float4* __restrict__ in,
                             ushort4* __restrict__ out, int n4) {
    int i = blockIdx.x * blockDim.x + threadIdx.x;
    if (i < n4) {
        float4 v = in[i];
        ushort4 o;
        o.x = f32_to_bf16_bits(v.x);
        o.y = f32_to_bf16_bits(v.y);
        o.z = f32_to_bf16_bits(v.z);
        o.w = f32_to_bf16_bits(v.w);
        out[i] = o;
    }
}

// ---------------- prep: transpose K x N fp32 -> N x K bf16 ----------------
__global__ void transpose_cvt(const float* __restrict__ in,
                              unsigned short* __restrict__ out,
                              int K, int N) {
    __shared__ float t[32][33];
    int n0 = blockIdx.x * 32, k0 = blockIdx.y * 32;
    int tx = threadIdx.x, ty = threadIdx.y;     // block (32,8)
    #pragma unroll
    for (int r = ty; r < 32; r += 8)
        t[r][tx] = in[(size_t)(k0 + r) * N + n0 + tx];
    __syncthreads();
    #pragma unroll
    for (int r = ty; r < 32; r += 8)
        out[(size_t)(n0 + r) * K + k0 + tx] = f32_to_bf16_bits(t[tx][r]);
}

// ------------- bf16 MFMA GEMM, BK=64 + 32x32x16 + XOR swizzle -------------
// C[M,N] = A[M,K] * Bt[N,K]^T.  128x128 tile, 256 thr = 4 waves, each wave
// a 64x64 quadrant of 2x2 32x32 MFMA tiles.  Staging: global_load_lds
// dwordx4, 8 issues/wave/K-step (BK=64).  LDS rows are 128 B (bank-aligned)
// so 16B chunks are XOR-swizzled: physical chunk = logical ^ (row&7),
// applied on the GLOBAL side of the DMA (LDS dst must stay linear per
// m104/m108) and mirrored in fragment reads.  2-barrier K-loop (the
// round-4/5 lesson: barrier-free variants lose more to occupancy/latency
// than the barrier drain costs).
template<int WITH_BIAS>
__global__ __launch_bounds__(256) void gemm_bf16_k64(
    const unsigned short* __restrict__ A,
    const unsigned short* __restrict__ Bt,
    void* __restrict__ Cout,
    const float* __restrict__ bias,
    int M, int N, int K)
{
    __shared__ unsigned short As[128][64];   // 128 B/row
    __shared__ unsigned short Bs[128][64];

    const int tid  = threadIdx.x;
    const int wave = tid >> 6;
    const int lane = tid & 63;
    const int l32  = lane & 31;
    const int hi   = lane >> 5;           // k-half selector
    const int l7   = lane & 7;
    const int waveM = (wave & 1) * 64;
    const int waveN = (wave >> 1) * 64;
    const int rowBase = blockIdx.y * 128;
    const int colBase = blockIdx.x * 128;

    float16v acc[2][2];
    #pragma unroll
    for (int i = 0; i < 2; i++)
        #pragma unroll
        for (int j = 0; j < 2; j++)
            acc[i][j] = (float16v)0.0f;

    // DMA geometry: one issue = 8 rows x 128 B; lane -> row drow=lane>>3,
    // physical chunk l7.  Logical chunk fetched = l7 ^ (row&7) = l7 ^ drow.
    const int drow = lane >> 3;
    const int lc   = l7 ^ drow;
    const unsigned short* gA = A  + (size_t)(rowBase + wave * 32 + drow) * K + lc * 8;
    const unsigned short* gB = Bt + (size_t)(colBase + wave * 32 + drow) * K + lc * 8;
    const size_t k8 = (size_t)8 * K;

    for (int k0 = 0; k0 < K; k0 += 64) {
        __syncthreads();                       // LDS safe to overwrite
        #pragma unroll
        for (int g = 0; g < 4; g++) {
            gload_lds16(gA + k0 + (size_t)g * k8, &As[wave * 32 + g * 8][0]);
            gload_lds16(gB + k0 + (size_t)g * k8, &Bs[wave * 32 + g * 8][0]);
        }
        __syncthreads();                       // vmcnt(0) drain -> data ready

        #pragma unroll
        for (int t = 0; t < 4; t++) {
            // A/B fragment: m|n = lane&31, k = hi*8 + j within K16 chunk t.
            // logical chunk = 2t + hi; physical = logical ^ (row&7), row&7 = l7.
            const int pc = ((2 * t + hi) ^ l7) * 8;
            short8 a0 = *(const short8*)&As[waveM + l32][pc];
            short8 a1 = *(const short8*)&As[waveM + 32 + l32][pc];
            short8 b0 = *(const short8*)&Bs[waveN + l32][pc];
            short8 b1 = *(const short8*)&Bs[waveN + 32 + l32][pc];
            acc[0][0] = __builtin_amdgcn_mfma_f32_32x32x16_bf16(a0, b0, acc[0][0], 0, 0, 0);
            acc[0][1] = __builtin_amdgcn_mfma_f32_32x32x16_bf16(a0, b1, acc[0][1], 0, 0, 0);
            acc[1][0] = __builtin_amdgcn_mfma_f32_32x32x16_bf16(a1, b0, acc[1][0], 0, 0, 0);
            acc[1][1] = __builtin_amdgcn_mfma_f32_32x32x16_bf16(a1, b1, acc[1][1], 0, 0, 0);
        }
    }

    // epilogue: D col = lane&31, row = (reg&3) + 8*(reg>>2) + 4*(lane>>5)
    #pragma unroll
    for (int i = 0; i < 2; i++) {
        #pragma unroll
        for (int j = 0; j < 2; j++) {
            const int col = colBase + waveN + j * 32 + l32;
            #pragma unroll
            for (int r = 0; r < 16; r++) {
                const int row = rowBase + waveM + i * 32
                              + (r & 3) + 8 * (r >> 2) + 4 * hi;
                float v = acc[i][j][r];
                if (WITH_BIAS) {
                    ((float*)Cout)[(size_t)row * N + col] = v + bias[col];
                } else {
                    ((unsigned short*)Cout)[(size_t)row * N + col] =
                        f32_to_bf16_bits(v);
                }
            }
        }
    }
}

// ---------------- per-token attention: wave-per-token, barrier-free --------
__global__ __launch_bounds__(256) void attn_tok(
    const unsigned short* __restrict__ qkv,   // NTOK x 3072 bf16
    const float* __restrict__ fcos,           // 4096 x 32
    const float* __restrict__ fsin,
    const float* __restrict__ gq,             // 64
    const float* __restrict__ gk,
    unsigned short* __restrict__ outb)        // NTOK x 1024 bf16
{
    __shared__ float kl[4][16][68];   // [wave][g][dim] stride 68: 2-way alias
    __shared__ float vl[4][16][68];

    const int tid  = threadIdx.x;
    const int wv   = tid >> 6;
    const int lane = tid & 63;
    const int h    = lane & 15;
    const int p    = lane >> 4;
    const int tok  = blockIdx.x * 4 + wv;
    const int n    = tok & (SEQN - 1);

    const unsigned short* base = qkv + (size_t)tok * K3 + h * 64 + p * 16;
    uint4 qr0 = *(const uint4*)(base);
    uint4 qr1 = *(const uint4*)(base + 8);
    uint4 kr0 = *(const uint4*)(base + DIM);
    uint4 kr1 = *(const uint4*)(base + DIM + 8);
    uint4 vr0 = *(const uint4*)(base + 2 * DIM);
    uint4 vr1 = *(const uint4*)(base + 2 * DIM + 8);

    float q[16], k[16], v[16];
    unpack_bf16x8(qr0, q); unpack_bf16x8(qr1, q + 8);
    unpack_bf16x8(kr0, k); unpack_bf16x8(kr1, k + 8);
    unpack_bf16x8(vr0, v); unpack_bf16x8(vr1, v + 8);

    // RMSNorm over the 64-dim head (reduce across the 4 p-slices)
    float ssq = 0.f, ssk = 0.f;
    #pragma unroll
    for (int i = 0; i < 16; i++) { ssq += q[i] * q[i]; ssk += k[i] * k[i]; }
    ssq += __shfl_xor(ssq, 16); ssq += __shfl_xor(ssq, 32);
    ssk += __shfl_xor(ssk, 16); ssk += __shfl_xor(ssk, 32);
    const float sq = 1.0f / (sqrtf(ssq) * 0.125f + 1e-6f);
    const float sk = 1.0f / (sqrtf(ssk) * 0.125f + 1e-6f);

    #pragma unroll
    for (int c = 0; c < 4; c++) {
        float4 gg = *(const float4*)(gq + p * 16 + c * 4);
        float4 gh = *(const float4*)(gk + p * 16 + c * 4);
        q[c*4+0] *= sq * gg.x; q[c*4+1] *= sq * gg.y;
        q[c*4+2] *= sq * gg.z; q[c*4+3] *= sq * gg.w;
        k[c*4+0] *= sk * gh.x; k[c*4+1] *= sk * gh.y;
        k[c*4+2] *= sk * gh.z; k[c*4+3] *= sk * gh.w;
    }

    // RoPE: local pair j -> global pair index 8p+j
    {
        const float* cb = fcos + n * 32 + p * 8;
        const float* sb = fsin + n * 32 + p * 8;
        float4 c0 = *(const float4*)cb, c1 = *(const float4*)(cb + 4);
        float4 s0 = *(const float4*)sb, s1 = *(const float4*)(sb + 4);
        float cs[8] = {c0.x,c0.y,c0.z,c0.w,c1.x,c1.y,c1.z,c1.w};
        float sn[8] = {s0.x,s0.y,s0.z,s0.w,s1.x,s1.y,s1.z,s1.w};
        #pragma unroll
        for (int j = 0; j < 8; j++) {
            float re = q[2*j], im = q[2*j+1];
            q[2*j]   = re * cs[j] - im * sn[j];
            q[2*j+1] = re * sn[j] + im * cs[j];
            re = k[2*j]; im = k[2*j+1];
            k[2*j]   = re * cs[j] - im * sn[j];
            k[2*j+1] = re * sn[j] + im * cs[j];
        }
    }

    // stage roped K and raw V into the per-wave LDS tile
    {
        float* krow = &kl[wv][h][p * 16];
        float* vrow = &vl[wv][h][p * 16];
        #pragma unroll
        for (int c = 0; c < 4; c++) {
            *(float4*)(krow + c*4) = make_float4(k[c*4], k[c*4+1], k[c*4+2], k[c*4+3]);
            *(float4*)(vrow + c*4) = make_float4(v[c*4], v[c*4+1], v[c*4+2], v[c*4+3]);
        }
    }

    // S[h][g] partial over this lane's 16 dims, then reduce across p
    float s[16];
    #pragma unroll
    for (int g = 0; g < 16; g++) {
        const float* kg = &kl[wv][g][p * 16];
        float4 a0 = *(const float4*)(kg);
        float4 a1 = *(const float4*)(kg + 4);
        float4 a2 = *(const float4*)(kg + 8);
        float4 a3 = *(const float4*)(kg + 12);
        s[g] = q[0]*a0.x + q[1]*a0.y + q[2]*a0.z + q[3]*a0.w
             + q[4]*a1.x + q[5]*a1.y + q[6]*a1.z + q[7]*a1.w
             + q[8]*a2.x + q[9]*a2.y + q[10]*a2.z + q[11]*a2.w
             + q[12]*a3.x + q[13]*a3.y + q[14]*a3.z + q[15]*a3.w;
    }
    #pragma unroll
    for (int g = 0; g < 16; g++) {
        s[g] += __shfl_xor(s[g], 16);
        s[g] += __shfl_xor(s[g], 32);
        s[g] *= 0.125f;
    }

    // lane-local softmax over g
    float m = s[0];
    #pragma unroll
    for (int g = 1; g < 16; g++) m = fmaxf(m, s[g]);
    float sum = 0.f;
    #pragma unroll
    for (int g = 0; g < 16; g++) { s[g] = __expf(s[g] - m); sum += s[g]; }
    const float inv = 1.0f / sum;

    // O[h][slice p] = sum_g P[g] * V[g][slice p]
    float o[16];
    #pragma unroll
    for (int i = 0; i < 16; i++) o[i] = 0.f;
    #pragma unroll
    for (int g = 0; g < 16; g++) {
        const float pg = s[g] * inv;
        const float* vg = &vl[wv][g][p * 16];
        float4 b0 = *(const float4*)(vg);
        float4 b1 = *(const float4*)(vg + 4);
        float4 b2 = *(const float4*)(vg + 8);
        float4 b3 = *(const float4*)(vg + 12);
        o[0]  += pg * b0.x; o[1]  += pg * b0.y; o[2]  += pg * b0.z; o[3]  += pg * b0.w;
        o[4]  += pg * b1.x; o[5]  += pg * b1.y; o[6]  += pg * b1.z; o[7]  += pg * b1.w;
        o[8]  += pg * b2.x; o[9]  += pg * b2.y; o[10] += pg * b2.z; o[11] += pg * b2.w;
        o[12] += pg * b3.x; o[13] += pg * b3.y; o[14] += pg * b3.z; o[15] += pg * b3.w;
    }

    uint4 r0, r1;
    r0.x = pack_bf16x2(o[0],  o[1]);  r0.y = pack_bf16x2(o[2],  o[3]);
    r0.z = pack_bf16x2(o[4],  o[5]);  r0.w = pack_bf16x2(o[6],  o[7]);
    r1.x = pack_bf16x2(o[8],  o[9]);  r1.y = pack_bf16x2(o[10], o[11]);
    r1.z = pack_bf16x2(o[12], o[13]); r1.w = pack_bf16x2(o[14], o[15]);
    unsigned short* ob = outb + (size_t)tok * DIM + h * 64 + p * 16;
    *(uint4*)(ob)     = r0;
    *(uint4*)(ob + 8) = r1;
}

// ---------------- launch ----------------
extern "C" void kernel_launch(void* const* d_in, const int* in_sizes, int n_in,
                              void* d_out, int out_size, void* d_ws, size_t ws_size,
                              hipStream_t stream) {
    const float* x      = (const float*)d_in[0];   // 16384 x 1024
    const float* fcos   = (const float*)d_in[1];   // 4096 x 32
    const float* fsin   = (const float*)d_in[2];
    const float* w_qkv  = (const float*)d_in[3];   // 1024 x 3072
    const float* g_q    = (const float*)d_in[4];
    const float* g_k    = (const float*)d_in[5];
    const float* w_proj = (const float*)d_in[6];   // 1024 x 1024
    const float* b_proj = (const float*)d_in[7];
    float* out = (float*)d_out;

    char* ws = (char*)d_ws;
    // workspace layout (bytes)
    unsigned short* xb      = (unsigned short*)(ws);                       // 33,554,432
    unsigned short* wqkvT   = (unsigned short*)(ws + 33554432);            //  6,291,456
    unsigned short* wprojT  = (unsigned short*)(ws + 39845888);            //  2,097,152
    unsigned short* qkv     = (unsigned short*)(ws + 41943040);            // 100,663,296
    unsigned short* attnout = (unsigned short*)(ws + 142606336);           // 33,554,432
    (void)ws_size; (void)in_sizes; (void)n_in; (void)out_size;

    // 1. casts / transposes
    {
        int n4 = (NTOK * DIM) / 4;   // 4,194,304
        cvt_f32_bf16<<<(n4 + 255) / 256, 256, 0, stream>>>(
            (const float4*)x, (ushort4*)xb, n4);
        transpose_cvt<<<dim3(K3 / 32, DIM / 32), dim3(32, 8), 0, stream>>>(
            w_qkv, wqkvT, DIM, K3);
        transpose_cvt<<<dim3(DIM / 32, DIM / 32), dim3(32, 8), 0, stream>>>(
            w_proj, wprojT, DIM, DIM);
    }
    // 2. qkv = x @ w_qkv   (bf16 out)
    gemm_bf16_k64<0><<<dim3(K3 / 128, NTOK / 128), 256, 0, stream>>>(
        xb, wqkvT, (void*)qkv, nullptr, NTOK, K3, DIM);
    // 3. per-token attention (wave per token, 4 tokens/block)
    attn_tok<<<NTOK / 4, 256, 0, stream>>>(qkv, fcos, fsin, g_q, g_k, attnout);
    // 4. out = attn @ w_proj + b   (fp32 out)
    gemm_bf16_k64<1><<<dim3(DIM / 128, NTOK / 128), 256, 0, stream>>>(
        attnout, wprojT, (void*)out, b_proj, NTOK, DIM, DIM);
}